// Round 1
// baseline (1676.705 us; speedup 1.0000x reference)
//
#include <hip/hip_runtime.h>

// TensorProduct: out[b,p,n,f] = parity[p] * sum_{l,m} x1[b,l,f]*x2[b,m,f]*cg[l,m,n]
// B=2048, L=M=9 ((lmax=2+1)^2), N=25, F=512, fp32.
// Memory-bound: ~285 MB total traffic -> ~45us floor @ 6.3 TB/s.

#define BATCH 2048
#define LDIM 9
#define NDIM 25
#define FDIM 512
#define FV (FDIM / 4)   // 128 float4 per (b,l) row

__global__ __launch_bounds__(256, 2) void tp_kernel(
    const float* __restrict__ x1,
    const float* __restrict__ x2,
    const float* __restrict__ cg,
    const float* __restrict__ parity,
    float* __restrict__ out)
{
    const int idx = blockIdx.x * 256 + threadIdx.x;   // 0 .. BATCH*FV-1
    const int b   = idx >> 7;                          // / FV
    const int fc  = idx & (FV - 1);

    const float4* x1v = (const float4*)x1 + b * LDIM * FV + fc;
    const float4* x2v = (const float4*)x2 + b * LDIM * FV + fc;

    float4 a[LDIM], q[LDIM];
#pragma unroll
    for (int l = 0; l < LDIM; ++l) a[l] = x1v[l * FV];
#pragma unroll
    for (int m = 0; m < LDIM; ++m) q[m] = x2v[m * FV];

    float4 acc[NDIM];
#pragma unroll
    for (int n = 0; n < NDIM; ++n) acc[n] = make_float4(0.f, 0.f, 0.f, 0.f);

    // Block-sparse CG contraction: blocks (A,Bb,C) with |A-Bb| <= C <= A+Bb.
    // All loop bounds constant-fold after unroll -> cg offsets are
    // compile-time -> wave-uniform s_loads (constant cache), acc[] stays
    // in registers (no dynamic indexing).
#pragma unroll
    for (int A = 0; A <= 2; ++A) {
#pragma unroll
        for (int Bb = 0; Bb <= 2; ++Bb) {
            const int cmin = (A > Bb) ? (A - Bb) : (Bb - A);
            const int cmax = A + Bb;   // <= 4 always
#pragma unroll
            for (int l = A * A; l < (A + 1) * (A + 1); ++l) {
#pragma unroll
                for (int m = Bb * Bb; m < (Bb + 1) * (Bb + 1); ++m) {
                    float4 p;
                    p.x = a[l].x * q[m].x;
                    p.y = a[l].y * q[m].y;
                    p.z = a[l].z * q[m].z;
                    p.w = a[l].w * q[m].w;
                    const float* __restrict__ cgrow = cg + (l * LDIM + m) * NDIM;
#pragma unroll
                    for (int C = cmin; C <= cmax; ++C) {
#pragma unroll
                        for (int n = C * C; n < (C + 1) * (C + 1); ++n) {
                            const float w = cgrow[n];
                            acc[n].x += w * p.x;
                            acc[n].y += w * p.y;
                            acc[n].z += w * p.z;
                            acc[n].w += w * p.w;
                        }
                    }
                }
            }
        }
    }

    const float p0 = parity[0];   // == 1.0f for this problem
    const float p1 = parity[1];   // == 0.0f -> zero-fills the p=1 plane

    float4* o0 = (float4*)out + (b * 2 + 0) * NDIM * FV + fc;
    float4* o1 = (float4*)out + (b * 2 + 1) * NDIM * FV + fc;
#pragma unroll
    for (int n = 0; n < NDIM; ++n) {
        float4 v0, v1;
        v0.x = acc[n].x * p0; v0.y = acc[n].y * p0;
        v0.z = acc[n].z * p0; v0.w = acc[n].w * p0;
        v1.x = acc[n].x * p1; v1.y = acc[n].y * p1;
        v1.z = acc[n].z * p1; v1.w = acc[n].w * p1;
        o0[n * FV] = v0;
        o1[n * FV] = v1;
    }
}

extern "C" void kernel_launch(void* const* d_in, const int* in_sizes, int n_in,
                              void* d_out, int out_size, void* d_ws, size_t ws_size,
                              hipStream_t stream) {
    const float* x1     = (const float*)d_in[0];
    const float* x2     = (const float*)d_in[1];
    const float* cg     = (const float*)d_in[2];
    const float* parity = (const float*)d_in[3];
    float* out          = (float*)d_out;

    const int total_threads = BATCH * FV;          // 262144
    dim3 grid(total_threads / 256), block(256);    // 1024 blocks
    hipLaunchKernelGGL(tp_kernel, grid, block, 0, stream, x1, x2, cg, parity, out);
}

// Round 2
// 297.479 us; speedup vs baseline: 5.6364x; 5.6364x over previous
//
#include <hip/hip_runtime.h>

// TensorProduct: out[b,p,n,f] = parity[p] * sum_{l,m} x1[b,l,f]*x2[b,m,f]*cg[l,m,n]
// B=2048, L=M=9, N=25, F=512, fp32.
// Memory-bound: ideal traffic = 75.5 MB read + 209.7 MB write -> ~45 us @ 6.3 TB/s.
//
// R1 lesson: variable inner-loop bounds broke full unroll -> acc[] demoted to
// scratch (VGPR=48, 7.7 GB HBM traffic). Fix: dense loops with LITERAL bounds
// so acc[n]/q[m] indices are compile-time after unroll -> register-resident.
// l-loop kept rolled (#pragma unroll 1): ~940-instr body fits I$; cg row
// offsets are wave-uniform -> scalar s_loads from constant cache.

#define BATCH 2048
#define LDIM 9
#define NDIM 25
#define FDIM 512
#define FV (FDIM / 4)   // 128 float4 per (b,l) row

__global__ __launch_bounds__(256, 2) void tp_kernel(
    const float* __restrict__ x1,
    const float* __restrict__ x2,
    const float* __restrict__ cg,
    const float* __restrict__ parity,
    float* __restrict__ out)
{
    const int idx = blockIdx.x * 256 + threadIdx.x;   // 0 .. BATCH*FV-1
    const int b   = idx >> 7;                          // / FV
    const int fc  = idx & (FV - 1);

    const float4* x1v = (const float4*)x1 + b * LDIM * FV + fc;
    const float4* x2v = (const float4*)x2 + b * LDIM * FV + fc;

    // x2 rows resident in registers (static indexing only after unroll)
    float4 q[LDIM];
#pragma unroll
    for (int m = 0; m < LDIM; ++m) q[m] = x2v[m * FV];

    float4 acc[NDIM];
#pragma unroll
    for (int n = 0; n < NDIM; ++n) acc[n] = make_float4(0.f, 0.f, 0.f, 0.f);

    // Dense contraction, literal bounds everywhere except the rolled l-loop.
    // l is wave-uniform -> cg row base is uniform -> s_load, no VMEM.
#pragma unroll 1
    for (int l = 0; l < LDIM; ++l) {
        const float4 a4 = x1v[l * FV];              // one coalesced 16B load/iter
        const float* __restrict__ cgl = cg + l * (LDIM * NDIM);
#pragma unroll
        for (int m = 0; m < LDIM; ++m) {
            float4 p;
            p.x = a4.x * q[m].x;
            p.y = a4.y * q[m].y;
            p.z = a4.z * q[m].z;
            p.w = a4.w * q[m].w;
            const float* __restrict__ cgrow = cgl + m * NDIM;
#pragma unroll
            for (int n = 0; n < NDIM; ++n) {
                const float w = cgrow[n];           // scalar (uniform) load
                acc[n].x += w * p.x;
                acc[n].y += w * p.y;
                acc[n].z += w * p.z;
                acc[n].w += w * p.w;
            }
        }
    }

    const float p0 = parity[0];   // 1.0f for this problem
    const float p1 = parity[1];   // 0.0f -> zero-fills the p=1 plane

    float4* o0 = (float4*)out + (b * 2 + 0) * NDIM * FV + fc;
    float4* o1 = (float4*)out + (b * 2 + 1) * NDIM * FV + fc;
#pragma unroll
    for (int n = 0; n < NDIM; ++n) {
        float4 v0, v1;
        v0.x = acc[n].x * p0; v0.y = acc[n].y * p0;
        v0.z = acc[n].z * p0; v0.w = acc[n].w * p0;
        v1.x = acc[n].x * p1; v1.y = acc[n].y * p1;
        v1.z = acc[n].z * p1; v1.w = acc[n].w * p1;
        o0[n * FV] = v0;
        o1[n * FV] = v1;
    }
}

extern "C" void kernel_launch(void* const* d_in, const int* in_sizes, int n_in,
                              void* d_out, int out_size, void* d_ws, size_t ws_size,
                              hipStream_t stream) {
    const float* x1     = (const float*)d_in[0];
    const float* x2     = (const float*)d_in[1];
    const float* cg     = (const float*)d_in[2];
    const float* parity = (const float*)d_in[3];
    float* out          = (float*)d_out;

    const int total_threads = BATCH * FV;          // 262144
    dim3 grid(total_threads / 256), block(256);    // 1024 blocks
    hipLaunchKernelGGL(tp_kernel, grid, block, 0, stream, x1, x2, cg, parity, out);
}

// Round 3
// 290.059 us; speedup vs baseline: 5.7806x; 1.0256x over previous
//
#include <hip/hip_runtime.h>

// TensorProduct: out[b,p,n,f] = parity[p] * sum_{l,m} x1[b,l,f]*x2[b,m,f]*cg[l,m,n]
// B=2048, L=M=9, N=25, F=512, fp32.
// Ideal traffic: 75.5 MB read + 209.7 MB write -> ~45 us @ 6.3 TB/s.
//
// R1: variable bounds -> acc[] spilled to scratch (7.7 GB traffic). Fixed.
// R2: dense contraction, ~95-100 us kernel. Latency-bound: per-l dependent
//     x1 load stalls + 2025 dense FMA4.
// R3: (a) block-sparse CG with LITERAL per-block (m,n) bounds via macros
//     (1225 FMA4, -40% VALU; body ~12 KB, fits I$);
//     (b) software prefetch of next x1 row across the rolled l-loops.

#define BATCH 2048
#define LDIM 9
#define NDIM 25
#define FDIM 512
#define FV (FDIM / 4)   // 128 float4 per (b,l) row

// p = a * q (elementwise float4)
#define MUL4(D, A, Q) \
    float4 D; D.x = (A).x * (Q).x; D.y = (A).y * (Q).y; \
              D.z = (A).z * (Q).z; D.w = (A).w * (Q).w;

// acc[n] += w[n] * p  for n in [N0, N1) — N0/N1 MUST be literals so acc
// indices are compile-time (register-resident). w is wave-uniform -> s_load.
#define FMA_RANGE(W, N0, N1, P) \
    _Pragma("unroll") \
    for (int n = (N0); n < (N1); ++n) { \
        const float c_ = (W)[n]; \
        acc[n].x += c_ * (P).x; \
        acc[n].y += c_ * (P).y; \
        acc[n].z += c_ * (P).z; \
        acc[n].w += c_ * (P).w; \
    }

__global__ __launch_bounds__(256, 2) void tp_kernel(
    const float* __restrict__ x1,
    const float* __restrict__ x2,
    const float* __restrict__ cg,
    const float* __restrict__ parity,
    float* __restrict__ out)
{
    const int idx = blockIdx.x * 256 + threadIdx.x;   // 0 .. BATCH*FV-1
    const int b   = idx >> 7;                          // / FV
    const int fc  = idx & (FV - 1);

    const float4* x1v = (const float4*)x1 + b * LDIM * FV + fc;
    const float4* x2v = (const float4*)x2 + b * LDIM * FV + fc;

    // x2 rows register-resident (static indexing after unroll)
    float4 q[LDIM];
#pragma unroll
    for (int m = 0; m < LDIM; ++m) q[m] = x2v[m * FV];

    float4 acc[NDIM];
#pragma unroll
    for (int n = 0; n < NDIM; ++n) acc[n] = make_float4(0.f, 0.f, 0.f, 0.f);

    // ---- A = 0 (l = 0): blocks (0,0)->n[0,1), (0,1)->n[1,4), (0,2)->n[4,9)
    float4 a_cur = x1v[0];
    float4 a_nxt = x1v[FV];            // prefetch row 1
    {
        const float* __restrict__ cgl = cg;   // l = 0
        { MUL4(p_, a_cur, q[0]); FMA_RANGE(cgl + 0 * NDIM, 0, 1, p_) }
#pragma unroll
        for (int m = 1; m < 4; ++m) { MUL4(p_, a_cur, q[m]); FMA_RANGE(cgl + m * NDIM, 1, 4, p_) }
#pragma unroll
        for (int m = 4; m < 9; ++m) { MUL4(p_, a_cur, q[m]); FMA_RANGE(cgl + m * NDIM, 4, 9, p_) }
    }
    a_cur = a_nxt;

    // ---- A = 1 (l = 1..3): (1,0)->n[1,4), (1,1)->n[0,9), (1,2)->n[1,16)
#pragma unroll 1
    for (int l = 1; l < 4; ++l) {
        a_nxt = x1v[(l + 1) * FV];     // prefetch before the FMA body
        const float* __restrict__ cgl = cg + l * (LDIM * NDIM);
        { MUL4(p_, a_cur, q[0]); FMA_RANGE(cgl + 0 * NDIM, 1, 4, p_) }
#pragma unroll
        for (int m = 1; m < 4; ++m) { MUL4(p_, a_cur, q[m]); FMA_RANGE(cgl + m * NDIM, 0, 9, p_) }
#pragma unroll
        for (int m = 4; m < 9; ++m) { MUL4(p_, a_cur, q[m]); FMA_RANGE(cgl + m * NDIM, 1, 16, p_) }
        a_cur = a_nxt;
    }

    // ---- A = 2 (l = 4..8): (2,0)->n[4,9), (2,1)->n[1,16), (2,2)->n[0,25)
#pragma unroll 1
    for (int l = 4; l < 9; ++l) {
        a_nxt = x1v[(l == 8 ? 8 : l + 1) * FV];   // clamp avoids OOB on last iter
        const float* __restrict__ cgl = cg + l * (LDIM * NDIM);
        { MUL4(p_, a_cur, q[0]); FMA_RANGE(cgl + 0 * NDIM, 4, 9, p_) }
#pragma unroll
        for (int m = 1; m < 4; ++m) { MUL4(p_, a_cur, q[m]); FMA_RANGE(cgl + m * NDIM, 1, 16, p_) }
#pragma unroll
        for (int m = 4; m < 9; ++m) { MUL4(p_, a_cur, q[m]); FMA_RANGE(cgl + m * NDIM, 0, 25, p_) }
        a_cur = a_nxt;
    }

    const float p0 = parity[0];   // 1.0f
    const float p1 = parity[1];   // 0.0f -> zero-fills the p=1 plane

    float4* o0 = (float4*)out + (b * 2 + 0) * NDIM * FV + fc;
    float4* o1 = (float4*)out + (b * 2 + 1) * NDIM * FV + fc;
#pragma unroll
    for (int n = 0; n < NDIM; ++n) {
        float4 v0, v1;
        v0.x = acc[n].x * p0; v0.y = acc[n].y * p0;
        v0.z = acc[n].z * p0; v0.w = acc[n].w * p0;
        v1.x = acc[n].x * p1; v1.y = acc[n].y * p1;
        v1.z = acc[n].z * p1; v1.w = acc[n].w * p1;
        o0[n * FV] = v0;
        o1[n * FV] = v1;
    }
}

extern "C" void kernel_launch(void* const* d_in, const int* in_sizes, int n_in,
                              void* d_out, int out_size, void* d_ws, size_t ws_size,
                              hipStream_t stream) {
    const float* x1     = (const float*)d_in[0];
    const float* x2     = (const float*)d_in[1];
    const float* cg     = (const float*)d_in[2];
    const float* parity = (const float*)d_in[3];
    float* out          = (float*)d_out;

    const int total_threads = BATCH * FV;          // 262144
    dim3 grid(total_threads / 256), block(256);    // 1024 blocks
    hipLaunchKernelGGL(tp_kernel, grid, block, 0, stream, x1, x2, cg, parity, out);
}

// Round 4
// 286.277 us; speedup vs baseline: 5.8569x; 1.0132x over previous
//
#include <hip/hip_runtime.h>

// TensorProduct: out[b,p,n,f] = parity[p] * sum_{l,m} x1[b,l,f]*x2[b,m,f]*cg[l,m,n]
// B=2048, L=M=9, N=25, F=512, fp32.
// Ideal traffic: 75.5 MB read + 209.7 MB write -> ~45 us @ 6.3 TB/s.
//
// R1: variable bounds -> acc[] spilled (7.7 GB traffic). Fixed w/ literal bounds.
// R2: dense, kernel ~97 us. R3: sparse+prefetch, ~90 us -> NOT VALU-bound;
//     latency-bound at 2 waves/SIMD (acc[25] float4 = ~180 VGPR).
// R4: float2 per thread -> acc=50 VGPR, ~100 total -> 4-5 waves/SIMD
//     (launch_bounds(256,4) caps at 128). 2x resident waves hides HBM
//     latency + store tail. Same total traffic/VALU.

#define BATCH 2048
#define LDIM 9
#define NDIM 25
#define FDIM 512
#define FV2 (FDIM / 2)   // 256 float2 per (b,l) row

#define MUL2(D, A, Q) \
    float2 D; D.x = (A).x * (Q).x; D.y = (A).y * (Q).y;

// acc[n] += w[n] * p for n in [N0,N1) — N0/N1 literal so acc stays in regs.
#define FMA_RANGE(W, N0, N1, P) \
    _Pragma("unroll") \
    for (int n = (N0); n < (N1); ++n) { \
        const float c_ = (W)[n]; \
        acc[n].x += c_ * (P).x; \
        acc[n].y += c_ * (P).y; \
    }

__global__ __launch_bounds__(256, 4) void tp_kernel(
    const float* __restrict__ x1,
    const float* __restrict__ x2,
    const float* __restrict__ cg,
    const float* __restrict__ parity,
    float* __restrict__ out)
{
    const int idx = blockIdx.x * 256 + threadIdx.x;   // 0 .. BATCH*FV2-1
    const int b   = idx >> 8;                          // / FV2
    const int fc  = idx & (FV2 - 1);

    const float2* x1v = (const float2*)x1 + b * LDIM * FV2 + fc;
    const float2* x2v = (const float2*)x2 + b * LDIM * FV2 + fc;

    float2 q[LDIM];
#pragma unroll
    for (int m = 0; m < LDIM; ++m) q[m] = x2v[m * FV2];

    float2 acc[NDIM];
#pragma unroll
    for (int n = 0; n < NDIM; ++n) acc[n] = make_float2(0.f, 0.f);

    // ---- A = 0 (l = 0): (0,0)->n[0,1), (0,1)->n[1,4), (0,2)->n[4,9)
    float2 a_cur = x1v[0];
    float2 a_nxt = x1v[FV2];           // prefetch row 1
    {
        const float* __restrict__ cgl = cg;   // l = 0
        { MUL2(p_, a_cur, q[0]); FMA_RANGE(cgl + 0 * NDIM, 0, 1, p_) }
#pragma unroll
        for (int m = 1; m < 4; ++m) { MUL2(p_, a_cur, q[m]); FMA_RANGE(cgl + m * NDIM, 1, 4, p_) }
#pragma unroll
        for (int m = 4; m < 9; ++m) { MUL2(p_, a_cur, q[m]); FMA_RANGE(cgl + m * NDIM, 4, 9, p_) }
    }
    a_cur = a_nxt;

    // ---- A = 1 (l = 1..3): (1,0)->n[1,4), (1,1)->n[0,9), (1,2)->n[1,16)
#pragma unroll 1
    for (int l = 1; l < 4; ++l) {
        a_nxt = x1v[(l + 1) * FV2];    // prefetch before FMA body
        const float* __restrict__ cgl = cg + l * (LDIM * NDIM);
        { MUL2(p_, a_cur, q[0]); FMA_RANGE(cgl + 0 * NDIM, 1, 4, p_) }
#pragma unroll
        for (int m = 1; m < 4; ++m) { MUL2(p_, a_cur, q[m]); FMA_RANGE(cgl + m * NDIM, 0, 9, p_) }
#pragma unroll
        for (int m = 4; m < 9; ++m) { MUL2(p_, a_cur, q[m]); FMA_RANGE(cgl + m * NDIM, 1, 16, p_) }
        a_cur = a_nxt;
    }

    // ---- A = 2 (l = 4..8): (2,0)->n[4,9), (2,1)->n[1,16), (2,2)->n[0,25)
#pragma unroll 1
    for (int l = 4; l < 9; ++l) {
        a_nxt = x1v[(l == 8 ? 8 : l + 1) * FV2];   // clamp avoids OOB
        const float* __restrict__ cgl = cg + l * (LDIM * NDIM);
        { MUL2(p_, a_cur, q[0]); FMA_RANGE(cgl + 0 * NDIM, 4, 9, p_) }
#pragma unroll
        for (int m = 1; m < 4; ++m) { MUL2(p_, a_cur, q[m]); FMA_RANGE(cgl + m * NDIM, 1, 16, p_) }
#pragma unroll
        for (int m = 4; m < 9; ++m) { MUL2(p_, a_cur, q[m]); FMA_RANGE(cgl + m * NDIM, 0, 25, p_) }
        a_cur = a_nxt;
    }

    const float p0 = parity[0];   // 1.0f
    const float p1 = parity[1];   // 0.0f -> zero-fills the p=1 plane

    float2* o0 = (float2*)out + (b * 2 + 0) * NDIM * FV2 + fc;
    float2* o1 = (float2*)out + (b * 2 + 1) * NDIM * FV2 + fc;
#pragma unroll
    for (int n = 0; n < NDIM; ++n) {
        float2 v0, v1;
        v0.x = acc[n].x * p0; v0.y = acc[n].y * p0;
        v1.x = acc[n].x * p1; v1.y = acc[n].y * p1;
        o0[n * FV2] = v0;
        o1[n * FV2] = v1;
    }
}

extern "C" void kernel_launch(void* const* d_in, const int* in_sizes, int n_in,
                              void* d_out, int out_size, void* d_ws, size_t ws_size,
                              hipStream_t stream) {
    const float* x1     = (const float*)d_in[0];
    const float* x2     = (const float*)d_in[1];
    const float* cg     = (const float*)d_in[2];
    const float* parity = (const float*)d_in[3];
    float* out          = (float*)d_out;

    const int total_threads = BATCH * FV2;         // 524288
    dim3 grid(total_threads / 256), block(256);    // 2048 blocks
    hipLaunchKernelGGL(tp_kernel, grid, block, 0, stream, x1, x2, cg, parity, out);
}